// Round 1
// 416.627 us; speedup vs baseline: 1.1440x; 1.1440x over previous
//
#include <hip/hip_runtime.h>
#include <hip/hip_bf16.h>

#define C_IN 64
#define H_IN 512
#define W_IN 512
#define D_OUT 128
#define OH 510
#define OW 510

typedef __bf16 bf16x8 __attribute__((ext_vector_type(8)));
typedef float  f32x4  __attribute__((ext_vector_type(4)));
typedef float  f32x2  __attribute__((ext_vector_type(2)));

#define TIN_ELEMS (H_IN * W_IN * C_IN)
#define TIN_BYTES ((size_t)TIN_ELEMS * 2)        // 32 MB
#define WT_BYTES  (9 * D_OUT * C_IN * 2)         // 147,456
#define WS_NEEDED (TIN_BYTES + WT_BYTES)

// ---------- pre-pass: kernels [D][C][3][3] fp32 -> wt[kpos][d][c] bf16 ----------
__global__ void prep_weights(const float* __restrict__ w, __bf16* __restrict__ wt) {
    int i = blockIdx.x * blockDim.x + threadIdx.x;
    if (i >= 9 * D_OUT * C_IN) return;
    int c    = i & 63;
    int d    = (i >> 6) & 127;
    int kpos = i >> 13;
    wt[i] = (__bf16)w[((d * C_IN) + c) * 9 + kpos];
}

// ---------- pre-pass: input [c][y][x] fp32 -> tin[y][x][c] bf16 ----------
__global__ __launch_bounds__(256, 4)
void transpose_in(const float* __restrict__ in, __bf16* __restrict__ tin) {
    __shared__ float ls[32 * 257];          // 32 c-rows, stride 257 dwords (bank-spread)
    const int b    = blockIdx.x;            // 1024
    const int y    = b >> 1;
    const int px0  = (b & 1) << 8;
    const int t    = threadIdx.x;
    const int wave = t >> 6;
    const int lane = t & 63;

    for (int cc = 0; cc < 2; cc++) {
        if (cc) __syncthreads();            // buffer reuse guard
#pragma unroll
        for (int j = 0; j < 8; j++) {
            const int cl = wave * 8 + j;    // chunk-local c
            f32x4 v = *(const f32x4*)&in[(cc * 32 + cl) * (H_IN * W_IN) + y * W_IN + px0 + lane * 4];
            *(f32x4*)&ls[cl * 257 + lane * 4] = v;
        }
        __syncthreads();
        const int oct = t & 3;              // c-octet within 32-chunk
        const int pxw = t >> 2;             // 0..63
#pragma unroll
        for (int pass = 0; pass < 4; pass++) {
            const int pxl = pass * 64 + pxw;
            bf16x8 v;
#pragma unroll
            for (int j = 0; j < 8; j++)
                v[j] = (__bf16)ls[(oct * 8 + j) * 257 + pxl];
            *(bf16x8*)&tin[((size_t)(y * W_IN) + px0 + pxl) * C_IN + cc * 32 + oct * 8] = v;
        }
    }
}

// ---------- main conv v3: block = 256 px x 32 d, weights shared via LDS ----------
// Round-3 restructure: previous block shape (64 px x 128 d, waves split d) forced
// 144 VGPRs of register-pinned weights per wave -> ~2 blocks/CU -> latency-bound
// (MfmaUtil 5.7 / VALU 3.3 / HBM 12.5%, Occupancy 22%). Now all 4 waves share one
// 32-d weight slice staged once in LDS (36,864 B, XOR-swizzled 16B units), which
// frees the registers for (a) 4 waves/SIMD occupancy and (b) a full bias prefetch
// issued BEFORE the main loop so cold-HBM bias latency hides under the MFMAs.
#define BPX 256
#define LO_STRIDE 260                        // dwords; 16B-aligned rows, bank-spread

__global__ __launch_bounds__(256, 4)
void conv_main(const __bf16* __restrict__ tin, const __bf16* __restrict__ wt,
               const float* __restrict__ bias, float* __restrict__ out) {
    __shared__ __align__(16) char smem[9 * 32 * 64 * 2];   // 36,864 B
    __bf16* lw = (__bf16*)smem;              // [9][32][64] bf16, swizzled
    float*  lo = (float*)smem;               // [32][260] f32 (33,280 B) after main loop

    const int b    = blockIdx.x;             // 510*2*4 = 4080
    const int dt   = b & 3;
    const int xt   = (b >> 2) & 1;
    const int y    = b >> 3;
    const int d0   = dt << 5;
    const int x0   = xt ? (OW - BPX) : 0;    // 0 or 254 (overlap px recomputed, same values)

    const int t    = threadIdx.x;
    const int wave = t >> 6;
    const int lane = t & 63;
    const int l15  = lane & 15;
    const int quad = lane >> 4;

    // ---- stage this block's 32-d weight slice into LDS (once) ----
    {
        const int dl  = t >> 3, oc = t & 7;
        const int ocs = (oc ^ (dl & 7)) * 8;   // XOR-swizzle 16B units within each row
#pragma unroll
        for (int kpos = 0; kpos < 9; kpos++) {
            bf16x8 v = *(const bf16x8*)(wt + kpos * (D_OUT * C_IN) + (d0 + dl) * C_IN + oc * 8);
            *(bf16x8*)&lw[(kpos * 32 + dl) * 64 + ocs] = v;
        }
    }
    __syncthreads();

    // ---- prefetch bias into registers; consumed only after the epilogue barrier,
    //      so its HBM latency hides under the whole main loop ----
    f32x2 bvals[16];
    const size_t ob = (size_t)(d0 + wave * 8) * (OH * OW) + (size_t)y * OW + x0 + lane * 4;
#pragma unroll
    for (int i = 0; i < 8; i++) {
        bvals[2 * i]     = *(const f32x2*)&bias[ob + (size_t)i * (OH * OW)];
        bvals[2 * i + 1] = *(const f32x2*)&bias[ob + (size_t)i * (OH * OW) + 2];
    }

    // ---- main loop: wave covers px = x0 + wave*64 + [0,64), d = d0 + [0,32) ----
    f32x4 acc[4][2];
#pragma unroll
    for (int pxg = 0; pxg < 4; pxg++)
#pragma unroll
        for (int dg = 0; dg < 2; dg++)
            acc[pxg][dg] = (f32x4){0.f, 0.f, 0.f, 0.f};

    const __bf16* tb = tin + ((size_t)y * W_IN + x0 + wave * 64) * C_IN + quad * 8;
#pragma unroll
    for (int kpos = 0; kpos < 9; kpos++) {
        const int ky = kpos / 3, kx = kpos % 3;
#pragma unroll
        for (int ch = 0; ch < 2; ch++) {
            const int us = (((ch * 4 + quad) ^ (l15 & 7)) * 8);   // swizzled c-unit
            bf16x8 w0 = *(const bf16x8*)&lw[(kpos * 32 + l15) * 64 + us];
            bf16x8 w1 = *(const bf16x8*)&lw[(kpos * 32 + 16 + l15) * 64 + us];
            const __bf16* base = tb + ((size_t)ky * W_IN + kx) * C_IN + ch * 32;
#pragma unroll
            for (int pxg = 0; pxg < 4; pxg++) {
                bf16x8 pf = *(const bf16x8*)(base + (pxg * 16 + l15) * C_IN);
                acc[pxg][0] = __builtin_amdgcn_mfma_f32_16x16x32_bf16(pf, w0, acc[pxg][0], 0, 0, 0);
                acc[pxg][1] = __builtin_amdgcn_mfma_f32_16x16x32_bf16(pf, w1, acc[pxg][1], 0, 0, 0);
            }
        }
    }

    // force bias loads to have been issued early (materialize here, after the loop)
#pragma unroll
    for (int i = 0; i < 16; i++) asm volatile("" : "+v"(bvals[i]));

    // ---- epilogue: LDS transpose (reuses weight buffer) + bias add, coalesced ----
    __syncthreads();                        // all lw reads done; safe to overwrite
#pragma unroll
    for (int pxg = 0; pxg < 4; pxg++)
#pragma unroll
        for (int dg = 0; dg < 2; dg++)
            *(f32x4*)&lo[(dg * 16 + l15) * LO_STRIDE + wave * 64 + pxg * 16 + quad * 4] = acc[pxg][dg];
    __syncthreads();
#pragma unroll
    for (int i = 0; i < 8; i++) {
        f32x4 v = *(const f32x4*)&lo[(wave * 8 + i) * LO_STRIDE + lane * 4];
        const size_t o = ob + (size_t)i * (OH * OW);
        // f32x2: (y*510 + x0) can be ≡2 mod 4, so 16B stores would misalign
        f32x2 r0 = { v[0] + bvals[2 * i][0],     v[1] + bvals[2 * i][1] };
        f32x2 r1 = { v[2] + bvals[2 * i + 1][0], v[3] + bvals[2 * i + 1][1] };
        *(f32x2*)&out[o]     = r0;
        *(f32x2*)&out[o + 2] = r1;
    }
}

// ---------- fallback (proven v1) if workspace is too small ----------
#define PXT 64
#define TCOL 66
#define TCPAD 72

__global__ __launch_bounds__(256, 4)
void conv_bias_fallback(const float* __restrict__ in, const __bf16* __restrict__ wt,
                        const float* __restrict__ bias, float* __restrict__ out) {
    __shared__ __bf16 tile[3 * TCOL * TCPAD];
    const int b  = blockIdx.x;
    const int y  = b >> 3;
    const int x0 = (b & 7) * PXT;
    const int tid = threadIdx.x;
    for (int idx = tid; idx < 3 * TCOL * C_IN; idx += 256) {
        int col = idx % TCOL;
        int t   = idx / TCOL;
        int r   = t % 3;
        int c   = t / 3;
        int gx  = x0 + col;
        if (gx > W_IN - 1) gx = W_IN - 1;
        tile[(r * TCOL + col) * TCPAD + c] = (__bf16)in[(c * H_IN + (y + r)) * W_IN + gx];
    }
    __syncthreads();
    const int wave = tid >> 6, lane = tid & 63;
    const int l15 = lane & 15, quad = lane >> 4;
    const int px_base = wave * 16;
    f32x4 acc[8];
#pragma unroll
    for (int i = 0; i < 8; i++) acc[i] = (f32x4){0.f, 0.f, 0.f, 0.f};
#pragma unroll
    for (int kpos = 0; kpos < 9; kpos++) {
        const int ky = kpos / 3, kx = kpos % 3;
#pragma unroll
        for (int ch = 0; ch < 2; ch++) {
            const int c0 = ch * 32;
            bf16x8 bfrag = *(const bf16x8*)&tile[(ky * TCOL + px_base + l15 + kx) * TCPAD + c0 + quad * 8];
            const __bf16* aptr = wt + (size_t)kpos * D_OUT * C_IN + l15 * C_IN + c0 + quad * 8;
#pragma unroll
            for (int ds = 0; ds < 8; ds++) {
                bf16x8 afrag = *(const bf16x8*)(aptr + ds * 16 * C_IN);
                acc[ds] = __builtin_amdgcn_mfma_f32_16x16x32_bf16(afrag, bfrag, acc[ds], 0, 0, 0);
            }
        }
    }
    const int gx = x0 + px_base + l15;
    if (gx < OW) {
#pragma unroll
        for (int ds = 0; ds < 8; ds++) {
            const int dbase = ds * 16 + quad * 4;
#pragma unroll
            for (int r = 0; r < 4; r++) {
                const size_t o = ((size_t)(dbase + r) * OH + y) * OW + gx;
                out[o] = acc[ds][r] + bias[o];
            }
        }
    }
}

extern "C" void kernel_launch(void* const* d_in, const int* in_sizes, int n_in,
                              void* d_out, int out_size, void* d_ws, size_t ws_size,
                              hipStream_t stream) {
    const float* in   = (const float*)d_in[0];
    const float* w    = (const float*)d_in[1];
    const float* bias = (const float*)d_in[2];
    float* out = (float*)d_out;

    if (ws_size >= WS_NEEDED) {
        __bf16* tin = (__bf16*)d_ws;
        __bf16* wt  = (__bf16*)((char*)d_ws + TIN_BYTES);
        prep_weights<<<(9 * D_OUT * C_IN + 255) / 256, 256, 0, stream>>>(w, wt);
        transpose_in<<<H_IN * 2, 256, 0, stream>>>(in, tin);
        conv_main<<<OH * 8, 256, 0, stream>>>(tin, wt, bias, out);
    } else {
        __bf16* wt = (__bf16*)d_ws;
        prep_weights<<<(9 * D_OUT * C_IN + 255) / 256, 256, 0, stream>>>(w, wt);
        conv_bias_fallback<<<OH * 8, 256, 0, stream>>>(in, wt, bias, out);
    }
}